// Round 7
// baseline (212.327 us; speedup 1.0000x reference)
//
#include <hip/hip_runtime.h>
#include <cstdint>
#include <cstddef>

#define Bq 4
#define T 2048
#define Dm 768
#define H 8
#define HD 96
#define BH 32
#define QEL ((size_t)BH*T*HD)     // q / v^T element count
#define KEL ((size_t)BH*T*128)    // padded K element count
// q pre-scaled by HD^-0.5 * log2(e): attention uses exp2 directly
#define QS 0.14724703336f
#define KVB 64

typedef unsigned int u32;
typedef unsigned long long u64;
typedef _Float16 f16x8 __attribute__((ext_vector_type(8)));
typedef _Float16 f16x4 __attribute__((ext_vector_type(4)));
typedef float f32x4 __attribute__((ext_vector_type(4)));

// ---------------------------------------------------------------------------
__global__ __launch_bounds__(256)
void cvt_f16(const float* __restrict__ in, _Float16* __restrict__ out, int n4)
{
    const int i = blockIdx.x * 256 + threadIdx.x;
    if (i < n4) {
        const float4 v = reinterpret_cast<const float4*>(in)[i];
        f16x4 h;
        h[0] = (_Float16)v.x; h[1] = (_Float16)v.y;
        h[2] = (_Float16)v.z; h[3] = (_Float16)v.w;
        reinterpret_cast<f16x4*>(out)[i] = h;
    }
}

// ---------------------------------------------------------------------------
// fp16 MFMA GEMM, BM=BN=128, BK=64, 4 waves, 64x64/wave, single-buffer LDS.
// 1D grid, bijective XCD swizzle (nwg % 8 == 0): each XCD gets a contiguous
// chunk of tiles ordered n-fastest -> A-panels L2-resident per XCD.
// LDS layout: 8 k8-planes [8][128][8] halves, fed linearly by
// global_load_lds width=16; frag reads are 2-way bank patterns (free).
// SCATTER=true: q -> qb[bh][t][96] (*QS); k -> kpd[bh][t][128] (d-padded);
//               v -> vtb[bh][d][T] (transposed).
// ---------------------------------------------------------------------------
template <bool SCATTER>
__global__ __launch_bounds__(256)
void gemm_mfma(const _Float16* __restrict__ A, const _Float16* __restrict__ Bw,
               _Float16* __restrict__ qb, _Float16* __restrict__ kpd,
               _Float16* __restrict__ vtb, float* __restrict__ C,
               int N, int nx)
{
    constexpr int K = Dm;
    __shared__ _Float16 As[8 * 128 * 8];
    __shared__ _Float16 Bs[8 * 128 * 8];

    const int tid  = threadIdx.x;
    const int lane = tid & 63;
    const int wid  = tid >> 6;
    const int li   = lane & 15;
    const int lg   = lane >> 4;
    const int wr   = wid >> 1;
    const int wc   = wid & 1;

    // bijective XCD swizzle: nwg = 8*q; chunk of q consecutive ids per XCD
    const int qch = gridDim.x >> 3;
    const int id  = (blockIdx.x & 7) * qch + (blockIdx.x >> 3);
    const int m0  = (id / nx) * 128;
    const int n0  = (id % nx) * 128;

    f32x4 acc[4][4];
#pragma unroll
    for (int i = 0; i < 4; ++i)
#pragma unroll
        for (int j = 0; j < 4; ++j) acc[i][j] = (f32x4)0.f;

    for (int k0 = 0; k0 < K; k0 += 64) {
        // stage 128x64 A and B tiles (8 insts per wave)
#pragma unroll
        for (int i = 0; i < 4; ++i) {
            const int s   = wid * 256 + i * 64 + lane;
            const int row = s & 127, pl = s >> 7;
            const _Float16* ga = A + (size_t)(m0 + row) * K + k0 + pl * 8;
            const _Float16* gb = Bw + (size_t)(n0 + row) * K + k0 + pl * 8;
            __builtin_amdgcn_global_load_lds(
                (const __attribute__((address_space(1))) void*)ga,
                (__attribute__((address_space(3))) void*)&As[(wid * 256 + i * 64) * 8],
                16, 0, 0);
            __builtin_amdgcn_global_load_lds(
                (const __attribute__((address_space(1))) void*)gb,
                (__attribute__((address_space(3))) void*)&Bs[(wid * 256 + i * 64) * 8],
                16, 0, 0);
        }
        __syncthreads();

#pragma unroll
        for (int c = 0; c < 2; ++c) {
            f16x8 af[4], bf[4];
#pragma unroll
            for (int i = 0; i < 4; ++i)
                af[i] = *reinterpret_cast<const f16x8*>(
                    &As[((c * 4 + lg) * 128 + wr * 64 + i * 16 + li) * 8]);
#pragma unroll
            for (int j = 0; j < 4; ++j)
                bf[j] = *reinterpret_cast<const f16x8*>(
                    &Bs[((c * 4 + lg) * 128 + wc * 64 + j * 16 + li) * 8]);
#pragma unroll
            for (int i = 0; i < 4; ++i)
#pragma unroll
                for (int j = 0; j < 4; ++j)
                    acc[i][j] = __builtin_amdgcn_mfma_f32_16x16x32_f16(
                        af[i], bf[j], acc[i][j], 0, 0, 0);
        }
        __syncthreads();
    }

#pragma unroll
    for (int i = 0; i < 4; ++i) {
#pragma unroll
        for (int r = 0; r < 4; ++r) {
            const int m = m0 + wr * 64 + i * 16 + lg * 4 + r;
            if (SCATTER) {
                const int b_ = m >> 11, t_ = m & 2047;
#pragma unroll
                for (int j = 0; j < 4; ++j) {
                    const int e = n0 + wc * 64 + j * 16 + li;
                    const int c = e / Dm;
                    const int rem = e - c * Dm;
                    const int h = rem / HD;
                    const int d = rem - h * HD;
                    const size_t bhx = (size_t)(b_ * H + h);
                    const float v = acc[i][j][r];
                    if (c == 0)
                        qb[(bhx * T + t_) * HD + d] = (_Float16)(v * QS);
                    else if (c == 1)
                        kpd[(bhx * T + t_) * 128 + d] = (_Float16)v;
                    else
                        vtb[(bhx * 96 + d) * T + t_] = (_Float16)v;
                }
            } else {
#pragma unroll
                for (int j = 0; j < 4; ++j) {
                    const int n = n0 + wc * 64 + j * 16 + li;
                    C[(size_t)m * N + n] = acc[i][j][r];
                }
            }
        }
    }
}

// ---------------------------------------------------------------------------
// MFMA flash attention, causal, fp16 in/out. Q pre-scaled (exp2 softmax).
// Block = 4 waves x 16 q rows (QBLK=64); KV tiles of 64, double-buffered with
// counted-vmcnt prefetch (global_load_lds, pre-swizzled source -> XOR-swizzled
// conflict-free ds_read_b128). K from padded [T][128]; V from V^T [96][T].
// ---------------------------------------------------------------------------
__global__ __launch_bounds__(256)
void attn_mfma(const _Float16* __restrict__ QG, const _Float16* __restrict__ KG,
               const _Float16* __restrict__ VtG, _Float16* __restrict__ Out)
{
    __shared__ __align__(16) _Float16 Klds[2][64 * 128];
    __shared__ __align__(16) _Float16 Vlds[2][96 * 64];
    __shared__ __align__(16) _Float16 Pl[4][16][72];

    const int tid  = threadIdx.x;
    const int lane = tid & 63;
    const int wid  = tid >> 6;
    const int lg   = lane >> 4;
    const int li   = lane & 15;

    const int bh     = blockIdx.x & 31;
    const int qt_blk = 31 - (blockIdx.x >> 5);   // heavy q-tiles first
    const int q0     = qt_blk * 64;
    const int q0w    = q0 + wid * 16;
    const int ntiles = qt_blk + 1;

    // Q fragments straight to registers (B-frag: col=li -> q row, k=d)
    f16x8 qf[3];
    {
        const _Float16* qrow = QG + ((size_t)bh * T + q0w + li) * HD;
#pragma unroll
        for (int ch = 0; ch < 3; ++ch)
            qf[ch] = *reinterpret_cast<const f16x8*>(qrow + ch * 32 + lg * 8);
    }

    const int rK = lane >> 4;                  // 0..3
    const int cK = (lane & 15) * 8;
    const int rV = lane >> 3;                  // 0..7
    const int cV = (lane & 7) * 8;
    auto STAGE = [&](int kb, int b) {
#pragma unroll
        for (int ii = 0; ii < 4; ++ii) {
            const int r  = wid * 16 + ii * 4 + rK;          // row in tile
            const int c0 = cK ^ (((ii * 4 + rK) & 7) << 3); // swizzled src col
            const _Float16* src = KG + ((size_t)(bh * T + kb + r)) * 128 + c0;
            __builtin_amdgcn_global_load_lds(
                (const __attribute__((address_space(1))) void*)src,
                (__attribute__((address_space(3))) void*)&Klds[b][(wid * 16 + ii * 4) * 128],
                16, 0, 0);
        }
#pragma unroll
        for (int jj = 0; jj < 3; ++jj) {
            const int r  = wid * 24 + jj * 8 + rV;          // d row
            const int c0 = cV ^ (rV << 3);
            const _Float16* src = VtG + ((size_t)(bh * 96 + r)) * T + kb + c0;
            __builtin_amdgcn_global_load_lds(
                (const __attribute__((address_space(1))) void*)src,
                (__attribute__((address_space(3))) void*)&Vlds[b][(wid * 24 + jj * 8) * 64],
                16, 0, 0);
        }
    };

    f32x4 acc[6];
#pragma unroll
    for (int dt = 0; dt < 6; ++dt) acc[dt] = (f32x4)0.f;
    float m_run = -1e30f, l_run = 0.f;

    STAGE(0, 0);
    int p = 0;
    for (int t = 0; t < ntiles; ++t) {
        const int kb = t * KVB;
        const bool has_next = (t + 1 < ntiles);
        if (has_next) {
            STAGE(kb + KVB, p ^ 1);
            asm volatile("s_waitcnt vmcnt(7)" ::: "memory");   // buf[p] done
        } else {
            asm volatile("s_waitcnt vmcnt(0)" ::: "memory");
        }
        __builtin_amdgcn_s_barrier();

        // per-wave causal bound: # of 16-row K sub-tiles with any valid k
        const int nkt = min(4, ((q0w + 15 - kb) >> 4) + 1);

        // K A-frags (row=li -> k row, k=d), swizzled read
        f16x8 kf[4][3];
#pragma unroll
        for (int kt = 0; kt < 4; ++kt)
            if (kt < nkt) {
#pragma unroll
                for (int ch = 0; ch < 3; ++ch) {
                    const int row = kt * 16 + li;
                    const int cs  = (ch * 32 + lg * 8) ^ ((row & 7) << 3);
                    kf[kt][ch] = *reinterpret_cast<const f16x8*>(
                        &Klds[p][row * 128 + cs]);
                }
            }

        // S^T = K @ Q
        f32x4 st[4];
#pragma unroll
        for (int kt = 0; kt < 4; ++kt) {
            st[kt] = (f32x4)0.f;
            if (kt < nkt) {
#pragma unroll
                for (int ch = 0; ch < 3; ++ch)
                    st[kt] = __builtin_amdgcn_mfma_f32_16x16x32_f16(
                        kf[kt][ch], qf[ch], st[kt], 0, 0, 0);
            }
        }

        // mask + row max (q = q0w + li; k = kb + kt*16 + lg*4 + rr)
        const int qg = q0w + li;
        float s[16];
        float m16 = -1e30f;
#pragma unroll
        for (int kt = 0; kt < 4; ++kt)
            if (kt < nkt) {
                const bool full = (kb + kt * 16 + 15 <= q0w);
#pragma unroll
                for (int rr = 0; rr < 4; ++rr) {
                    float v = st[kt][rr];
                    if (!full) {
                        const int kg = kb + kt * 16 + lg * 4 + rr;
                        v = (kg <= qg) ? v : -1e30f;
                    }
                    s[kt * 4 + rr] = v;
                    m16 = fmaxf(m16, v);
                }
            }
        m16 = fmaxf(m16, __shfl_xor(m16, 16));
        m16 = fmaxf(m16, __shfl_xor(m16, 32));

        // defer-max: rescale only when max grew by > 8 (log2 domain)
        if (!__all(m16 <= m_run + 8.0f)) {
            const float m_new = fmaxf(m_run, m16);
            const float corr  = __builtin_amdgcn_exp2f(m_run - m_new);
            l_run *= corr;
            float cr[4];
#pragma unroll
            for (int rr = 0; rr < 4; ++rr) cr[rr] = __shfl(corr, lg * 4 + rr);
#pragma unroll
            for (int dt = 0; dt < 6; ++dt)
#pragma unroll
                for (int rr = 0; rr < 4; ++rr) acc[dt][rr] *= cr[rr];
            m_run = m_new;
        }

        float pr[16], ls = 0.f;
#pragma unroll
        for (int kt = 0; kt < 4; ++kt)
            if (kt < nkt) {
#pragma unroll
                for (int rr = 0; rr < 4; ++rr) {
                    pr[kt * 4 + rr] = __builtin_amdgcn_exp2f(s[kt * 4 + rr] - m_run);
                    ls += pr[kt * 4 + rr];
                }
            }
        ls += __shfl_xor(ls, 16);
        ls += __shfl_xor(ls, 32);
        l_run += ls;

        // stage P to wave-private LDS (u64 per sub-tile); zero odd remainder
#pragma unroll
        for (int kt = 0; kt < 4; ++kt)
            if (kt < nkt) {
                f16x4 pk;
                pk[0] = (_Float16)pr[kt * 4 + 0]; pk[1] = (_Float16)pr[kt * 4 + 1];
                pk[2] = (_Float16)pr[kt * 4 + 2]; pk[3] = (_Float16)pr[kt * 4 + 3];
                *reinterpret_cast<u64*>(&Pl[wid][li][kt * 16 + lg * 4]) =
                    __builtin_bit_cast(u64, pk);
            }
        if (nkt & 1)
            *reinterpret_cast<u64*>(&Pl[wid][li][nkt * 16 + lg * 4]) = 0ull;

        // PV: per 32-k chunk, A=P frag, B=V frag (row=d, swizzled read)
        const int npc = (nkt + 1) >> 1;
#pragma unroll
        for (int pc = 0; pc < 2; ++pc)
            if (pc < npc) {
                const f16x8 pf = *reinterpret_cast<const f16x8*>(
                    &Pl[wid][li][pc * 32 + lg * 8]);
#pragma unroll
                for (int dt = 0; dt < 6; ++dt) {
                    const int row = dt * 16 + li;
                    const int cs  = (pc * 32 + lg * 8) ^ ((row & 7) << 3);
                    const f16x8 vf = *reinterpret_cast<const f16x8*>(
                        &Vlds[p][row * 64 + cs]);
                    acc[dt] = __builtin_amdgcn_mfma_f32_16x16x32_f16(
                        pf, vf, acc[dt], 0, 0, 0);
                }
            }

        asm volatile("s_waitcnt lgkmcnt(0)" ::: "memory");
        __builtin_amdgcn_s_barrier();   // all reads of buf[p] done
        p ^= 1;
    }

    // epilogue: normalize, store fp16 to ao[B][T][768]
    const int ob = bh >> 3, oh = bh & 7;
#pragma unroll
    for (int rr = 0; rr < 4; ++rr) {
        const float linv = 1.0f / __shfl(l_run, lg * 4 + rr);
        const int qg2 = q0w + lg * 4 + rr;
        _Float16* op = Out + ((size_t)(ob * T + qg2)) * Dm + oh * HD;
#pragma unroll
        for (int dt = 0; dt < 6; ++dt)
            op[dt * 16 + li] = (_Float16)(acc[dt][rr] * linv);
    }
}

// ---------------------------------------------------------------------------
extern "C" void kernel_launch(void* const* d_in, const int* in_sizes, int n_in,
                              void* d_out, int out_size, void* d_ws, size_t ws_size,
                              hipStream_t stream)
{
    const float* x     = (const float*)d_in[0];
    const float* w_qkv = (const float*)d_in[1];
    const float* w_out = (const float*)d_in[2];
    // d_in[3] = leech kernel: orthogonal -> cancels in q.kT, ignored.

    _Float16* qb  = (_Float16*)d_ws;                 // [BH][T][96]
    _Float16* kpd = qb + QEL;                        // [BH][T][128]
    _Float16* vtb = kpd + KEL;                       // [BH][96][T]
    _Float16* aoh = vtb + QEL;                       // [B*T][768]
    _Float16* xh  = aoh + (size_t)Bq * T * Dm;
    _Float16* wqh = xh + (size_t)Bq * T * Dm;
    _Float16* woh = wqh + (size_t)3 * Dm * Dm;
    float* out = (float*)d_out;

    const int M = Bq * T;  // 8192

    cvt_f16<<<dim3((M * Dm) / 4 / 256), dim3(256), 0, stream>>>(x, xh, M * Dm / 4);
    cvt_f16<<<dim3((3 * Dm * Dm) / 4 / 256), dim3(256), 0, stream>>>(w_qkv, wqh, 3 * Dm * Dm / 4);
    cvt_f16<<<dim3((Dm * Dm) / 4 / 256), dim3(256), 0, stream>>>(w_out, woh, Dm * Dm / 4);

    // qkv projection: grid 1152 = (2304/128)*(8192/128), %8==0 -> swizzle ok
    gemm_mfma<true><<<dim3((3 * Dm / 128) * (M / 128)), dim3(256), 0, stream>>>(
        xh, wqh, qb, kpd, vtb, nullptr, 3 * Dm, 3 * Dm / 128);

    attn_mfma<<<dim3(BH * (T / 64)), dim3(256), 0, stream>>>(qb, kpd, vtb, aoh);

    // out projection: grid 384 = (768/128)*(8192/128), %8==0 -> swizzle ok
    gemm_mfma<false><<<dim3((Dm / 128) * (M / 128)), dim3(256), 0, stream>>>(
        aoh, woh, nullptr, nullptr, nullptr, out, Dm, Dm / 128);
}

// Round 8
// 176.224 us; speedup vs baseline: 1.2049x; 1.2049x over previous
//
#include <hip/hip_runtime.h>
#include <cstdint>
#include <cstddef>

#define Bq 4
#define T 2048
#define Dm 768
#define H 8
#define HD 96
#define BH 32
#define QEL ((size_t)BH*T*HD)     // q / v^T element count
#define KEL ((size_t)BH*T*128)    // padded K element count
#define PSTRIDE 98304             // tiled panel stride = (768/8)*128*8 elems
// q pre-scaled by HD^-0.5 * log2(e): attention uses exp2 directly
#define QS 0.14724703336f
#define KVB 64

typedef unsigned int u32;
typedef unsigned long long u64;
typedef _Float16 f16x8 __attribute__((ext_vector_type(8)));
typedef _Float16 f16x4 __attribute__((ext_vector_type(4)));
typedef float f32x4 __attribute__((ext_vector_type(4)));

// ---------------------------------------------------------------------------
// f32 [R][768] row-major -> fp16 tiled [R/128][96][128][8].
// One wave per (kc, 64-row block): reads gather (32B/lane), writes 1KB
// contiguous per wave (lane-consecutive 16B chunks).
// ---------------------------------------------------------------------------
__global__ __launch_bounds__(256)
void cvt_tile(const float* __restrict__ in, _Float16* __restrict__ out)
{
    const int tid  = threadIdx.x;
    const int lane = tid & 63;
    const int gw   = (blockIdx.x * 256 + tid) >> 6;
    const int kc   = gw % 96;
    const int row  = (gw / 96) * 64 + lane;
    const float4 a = *reinterpret_cast<const float4*>(in + (size_t)row * 768 + kc * 8);
    const float4 b = *reinterpret_cast<const float4*>(in + (size_t)row * 768 + kc * 8 + 4);
    f16x8 h;
    h[0] = (_Float16)a.x; h[1] = (_Float16)a.y; h[2] = (_Float16)a.z; h[3] = (_Float16)a.w;
    h[4] = (_Float16)b.x; h[5] = (_Float16)b.y; h[6] = (_Float16)b.z; h[7] = (_Float16)b.w;
    *reinterpret_cast<f16x8*>(
        out + (size_t)(row >> 7) * PSTRIDE + (size_t)kc * 1024 + (row & 127) * 8) = h;
}

// ---------------------------------------------------------------------------
// fp16 MFMA GEMM on TILED inputs. BM=BN=128, BK=64, 4 waves, 64x64/wave.
// Staging: 8 x global_load_lds(16B) per wave per K-step, each 1KB contiguous
// (tiled global layout == LDS k-plane layout [8][128][8]). Frag reads are
// 2-way bank patterns (free). 1D grid + bijective XCD swizzle.
// SCATTER=true: q -> qb[bh][t][96] (*QS); k -> kpd[bh][t][128] (d-padded);
//               v -> vtb[bh][d][T] (transposed).
// ---------------------------------------------------------------------------
template <bool SCATTER>
__global__ __launch_bounds__(256)
void gemm_mfma(const _Float16* __restrict__ At, const _Float16* __restrict__ Bt,
               _Float16* __restrict__ qb, _Float16* __restrict__ kpd,
               _Float16* __restrict__ vtb, float* __restrict__ C,
               int N, int nx)
{
    __shared__ _Float16 As[8 * 128 * 8];
    __shared__ _Float16 Bs[8 * 128 * 8];

    const int tid  = threadIdx.x;
    const int lane = tid & 63;
    const int wid  = tid >> 6;
    const int li   = lane & 15;
    const int lg   = lane >> 4;
    const int wr   = wid >> 1;
    const int wc   = wid & 1;

    const int qch = gridDim.x >> 3;
    const int id  = (blockIdx.x & 7) * qch + (blockIdx.x >> 3);
    const int m0  = (id / nx) * 128;
    const int n0  = (id % nx) * 128;

    const _Float16* baseA = At + (size_t)(m0 >> 7) * PSTRIDE;
    const _Float16* baseB = Bt + (size_t)(n0 >> 7) * PSTRIDE;

    f32x4 acc[4][4];
#pragma unroll
    for (int i = 0; i < 4; ++i)
#pragma unroll
        for (int j = 0; j < 4; ++j) acc[i][j] = (f32x4)0.f;

    for (int k0 = 0; k0 < Dm; k0 += 64) {
        const _Float16* pa = baseA + (k0 >> 3) * 1024;
        const _Float16* pb = baseB + (k0 >> 3) * 1024;
#pragma unroll
        for (int i = 0; i < 4; ++i) {
            const int s = wid * 64 + i * 256;        // wave-uniform slot base
            __builtin_amdgcn_global_load_lds(
                (const __attribute__((address_space(1))) void*)(pa + (size_t)(s + lane) * 8),
                (__attribute__((address_space(3))) void*)&As[s * 8], 16, 0, 0);
            __builtin_amdgcn_global_load_lds(
                (const __attribute__((address_space(1))) void*)(pb + (size_t)(s + lane) * 8),
                (__attribute__((address_space(3))) void*)&Bs[s * 8], 16, 0, 0);
        }
        __syncthreads();

#pragma unroll
        for (int c = 0; c < 2; ++c) {
            f16x8 af[4], bf[4];
#pragma unroll
            for (int i = 0; i < 4; ++i)
                af[i] = *reinterpret_cast<const f16x8*>(
                    &As[((c * 4 + lg) * 128 + wr * 64 + i * 16 + li) * 8]);
#pragma unroll
            for (int j = 0; j < 4; ++j)
                bf[j] = *reinterpret_cast<const f16x8*>(
                    &Bs[((c * 4 + lg) * 128 + wc * 64 + j * 16 + li) * 8]);
#pragma unroll
            for (int i = 0; i < 4; ++i)
#pragma unroll
                for (int j = 0; j < 4; ++j)
                    acc[i][j] = __builtin_amdgcn_mfma_f32_16x16x32_f16(
                        af[i], bf[j], acc[i][j], 0, 0, 0);
        }
        __syncthreads();
    }

#pragma unroll
    for (int i = 0; i < 4; ++i) {
#pragma unroll
        for (int r = 0; r < 4; ++r) {
            const int m = m0 + wr * 64 + i * 16 + lg * 4 + r;
            if (SCATTER) {
                const int b_ = m >> 11, t_ = m & 2047;
#pragma unroll
                for (int j = 0; j < 4; ++j) {
                    const int e = n0 + wc * 64 + j * 16 + li;
                    const int c = e / Dm;
                    const int rem = e - c * Dm;
                    const int h = rem / HD;
                    const int d = rem - h * HD;
                    const size_t bhx = (size_t)(b_ * H + h);
                    const float v = acc[i][j][r];
                    if (c == 0)
                        qb[(bhx * T + t_) * HD + d] = (_Float16)(v * QS);
                    else if (c == 1)
                        kpd[(bhx * T + t_) * 128 + d] = (_Float16)v;
                    else
                        vtb[(bhx * 96 + d) * T + t_] = (_Float16)v;
                }
            } else {
#pragma unroll
                for (int j = 0; j < 4; ++j) {
                    const int n = n0 + wc * 64 + j * 16 + li;
                    C[(size_t)m * N + n] = acc[i][j][r];
                }
            }
        }
    }
}

// ---------------------------------------------------------------------------
// MFMA flash attention, causal, fp16 in/out. Q pre-scaled (exp2 softmax).
// Block = 4 waves x 16 q rows (QBLK=64); KV tiles of 64, double-buffered with
// counted-vmcnt prefetch (global_load_lds, pre-swizzled source -> XOR-swizzled
// conflict-free ds_read_b128). K from padded [T][128]; V from V^T [96][T].
// Output written in TILED fp16 layout for the out-proj GEMM.
// ---------------------------------------------------------------------------
__global__ __launch_bounds__(256)
void attn_mfma(const _Float16* __restrict__ QG, const _Float16* __restrict__ KG,
               const _Float16* __restrict__ VtG, _Float16* __restrict__ aoh)
{
    __shared__ __align__(16) _Float16 Klds[2][64 * 128];
    __shared__ __align__(16) _Float16 Vlds[2][96 * 64];
    __shared__ __align__(16) _Float16 Pl[4][16][72];

    const int tid  = threadIdx.x;
    const int lane = tid & 63;
    const int wid  = tid >> 6;
    const int lg   = lane >> 4;
    const int li   = lane & 15;

    const int bh     = blockIdx.x & 31;
    const int qt_blk = 31 - (blockIdx.x >> 5);   // heavy q-tiles first
    const int q0     = qt_blk * 64;
    const int q0w    = q0 + wid * 16;
    const int ntiles = qt_blk + 1;

    // Q fragments straight to registers (B-frag: col=li -> q row, k=d)
    f16x8 qf[3];
    {
        const _Float16* qrow = QG + ((size_t)bh * T + q0w + li) * HD;
#pragma unroll
        for (int ch = 0; ch < 3; ++ch)
            qf[ch] = *reinterpret_cast<const f16x8*>(qrow + ch * 32 + lg * 8);
    }

    const int rK = lane >> 4;                  // 0..3
    const int cK = (lane & 15) * 8;
    const int rV = lane >> 3;                  // 0..7
    const int cV = (lane & 7) * 8;
    auto STAGE = [&](int kb, int b) {
#pragma unroll
        for (int ii = 0; ii < 4; ++ii) {
            const int r  = wid * 16 + ii * 4 + rK;          // row in tile
            const int c0 = cK ^ (((ii * 4 + rK) & 7) << 3); // swizzled src col
            const _Float16* src = KG + ((size_t)(bh * T + kb + r)) * 128 + c0;
            __builtin_amdgcn_global_load_lds(
                (const __attribute__((address_space(1))) void*)src,
                (__attribute__((address_space(3))) void*)&Klds[b][(wid * 16 + ii * 4) * 128],
                16, 0, 0);
        }
#pragma unroll
        for (int jj = 0; jj < 3; ++jj) {
            const int r  = wid * 24 + jj * 8 + rV;          // d row
            const int c0 = cV ^ (rV << 3);
            const _Float16* src = VtG + ((size_t)(bh * 96 + r)) * T + kb + c0;
            __builtin_amdgcn_global_load_lds(
                (const __attribute__((address_space(1))) void*)src,
                (__attribute__((address_space(3))) void*)&Vlds[b][(wid * 24 + jj * 8) * 64],
                16, 0, 0);
        }
    };

    f32x4 acc[6];
#pragma unroll
    for (int dt = 0; dt < 6; ++dt) acc[dt] = (f32x4)0.f;
    float m_run = -1e30f, l_run = 0.f;

    STAGE(0, 0);
    int p = 0;
    for (int t = 0; t < ntiles; ++t) {
        const int kb = t * KVB;
        const bool has_next = (t + 1 < ntiles);
        if (has_next) {
            STAGE(kb + KVB, p ^ 1);
            asm volatile("s_waitcnt vmcnt(7)" ::: "memory");   // buf[p] done
        } else {
            asm volatile("s_waitcnt vmcnt(0)" ::: "memory");
        }
        __builtin_amdgcn_s_barrier();

        // per-wave causal bound: # of 16-row K sub-tiles with any valid k
        const int nkt = min(4, ((q0w + 15 - kb) >> 4) + 1);

        // K A-frags (row=li -> k row, k=d), swizzled read
        f16x8 kf[4][3];
#pragma unroll
        for (int kt = 0; kt < 4; ++kt)
            if (kt < nkt) {
#pragma unroll
                for (int ch = 0; ch < 3; ++ch) {
                    const int row = kt * 16 + li;
                    const int cs  = (ch * 32 + lg * 8) ^ ((row & 7) << 3);
                    kf[kt][ch] = *reinterpret_cast<const f16x8*>(
                        &Klds[p][row * 128 + cs]);
                }
            }

        // S^T = K @ Q
        f32x4 st[4];
#pragma unroll
        for (int kt = 0; kt < 4; ++kt) {
            st[kt] = (f32x4)0.f;
            if (kt < nkt) {
#pragma unroll
                for (int ch = 0; ch < 3; ++ch)
                    st[kt] = __builtin_amdgcn_mfma_f32_16x16x32_f16(
                        kf[kt][ch], qf[ch], st[kt], 0, 0, 0);
            }
        }

        // mask + row max (q = q0w + li; k = kb + kt*16 + lg*4 + rr)
        const int qg = q0w + li;
        float s[16];
        float m16 = -1e30f;
#pragma unroll
        for (int kt = 0; kt < 4; ++kt)
            if (kt < nkt) {
                const bool full = (kb + kt * 16 + 15 <= q0w);
#pragma unroll
                for (int rr = 0; rr < 4; ++rr) {
                    float v = st[kt][rr];
                    if (!full) {
                        const int kg = kb + kt * 16 + lg * 4 + rr;
                        v = (kg <= qg) ? v : -1e30f;
                    }
                    s[kt * 4 + rr] = v;
                    m16 = fmaxf(m16, v);
                }
            }
        m16 = fmaxf(m16, __shfl_xor(m16, 16));
        m16 = fmaxf(m16, __shfl_xor(m16, 32));

        // defer-max: rescale only when max grew by > 8 (log2 domain)
        if (!__all(m16 <= m_run + 8.0f)) {
            const float m_new = fmaxf(m_run, m16);
            const float corr  = __builtin_amdgcn_exp2f(m_run - m_new);
            l_run *= corr;
            float cr[4];
#pragma unroll
            for (int rr = 0; rr < 4; ++rr) cr[rr] = __shfl(corr, lg * 4 + rr);
#pragma unroll
            for (int dt = 0; dt < 6; ++dt)
#pragma unroll
                for (int rr = 0; rr < 4; ++rr) acc[dt][rr] *= cr[rr];
            m_run = m_new;
        }

        float pr[16], ls = 0.f;
#pragma unroll
        for (int kt = 0; kt < 4; ++kt)
            if (kt < nkt) {
#pragma unroll
                for (int rr = 0; rr < 4; ++rr) {
                    pr[kt * 4 + rr] = __builtin_amdgcn_exp2f(s[kt * 4 + rr] - m_run);
                    ls += pr[kt * 4 + rr];
                }
            }
        ls += __shfl_xor(ls, 16);
        ls += __shfl_xor(ls, 32);
        l_run += ls;

        // stage P to wave-private LDS (u64 per sub-tile); zero odd remainder
#pragma unroll
        for (int kt = 0; kt < 4; ++kt)
            if (kt < nkt) {
                f16x4 pk;
                pk[0] = (_Float16)pr[kt * 4 + 0]; pk[1] = (_Float16)pr[kt * 4 + 1];
                pk[2] = (_Float16)pr[kt * 4 + 2]; pk[3] = (_Float16)pr[kt * 4 + 3];
                *reinterpret_cast<u64*>(&Pl[wid][li][kt * 16 + lg * 4]) =
                    __builtin_bit_cast(u64, pk);
            }
        if (nkt & 1)
            *reinterpret_cast<u64*>(&Pl[wid][li][nkt * 16 + lg * 4]) = 0ull;

        // PV: per 32-k chunk, A=P frag, B=V frag (row=d, swizzled read)
        const int npc = (nkt + 1) >> 1;
#pragma unroll
        for (int pc = 0; pc < 2; ++pc)
            if (pc < npc) {
                const f16x8 pf = *reinterpret_cast<const f16x8*>(
                    &Pl[wid][li][pc * 32 + lg * 8]);
#pragma unroll
                for (int dt = 0; dt < 6; ++dt) {
                    const int row = dt * 16 + li;
                    const int cs  = (pc * 32 + lg * 8) ^ ((row & 7) << 3);
                    const f16x8 vf = *reinterpret_cast<const f16x8*>(
                        &Vlds[p][row * 64 + cs]);
                    acc[dt] = __builtin_amdgcn_mfma_f32_16x16x32_f16(
                        pf, vf, acc[dt], 0, 0, 0);
                }
            }

        asm volatile("s_waitcnt lgkmcnt(0)" ::: "memory");
        __builtin_amdgcn_s_barrier();   // all reads of buf[p] done
        p ^= 1;
    }

    // epilogue: normalize, store fp16 in TILED layout [m/128][96][128][8]
    const int ob = bh >> 3, oh = bh & 7;
#pragma unroll
    for (int rr = 0; rr < 4; ++rr) {
        const float linv = 1.0f / __shfl(l_run, lg * 4 + rr);
        const int m = ob * T + q0w + lg * 4 + rr;
        _Float16* op = aoh + (size_t)(m >> 7) * PSTRIDE + (size_t)(m & 127) * 8
                     + (size_t)(oh * 12 + (li >> 3)) * 1024 + (li & 7);
#pragma unroll
        for (int dt = 0; dt < 6; ++dt)
            op[dt * 2048] = (_Float16)(acc[dt][rr] * linv);
    }
}

// ---------------------------------------------------------------------------
extern "C" void kernel_launch(void* const* d_in, const int* in_sizes, int n_in,
                              void* d_out, int out_size, void* d_ws, size_t ws_size,
                              hipStream_t stream)
{
    const float* x     = (const float*)d_in[0];
    const float* w_qkv = (const float*)d_in[1];
    const float* w_out = (const float*)d_in[2];
    // d_in[3] = leech kernel: orthogonal -> cancels in q.kT, ignored.

    _Float16* qb  = (_Float16*)d_ws;                 // [BH][T][96]
    _Float16* kpd = qb + QEL;                        // [BH][T][128]
    _Float16* vtb = kpd + KEL;                       // [BH][96][T]
    _Float16* aoh = vtb + QEL;                       // tiled [64][96][128][8]
    _Float16* xh  = aoh + (size_t)Bq * T * Dm;       // tiled [64][96][128][8]
    _Float16* wqh = xh + (size_t)Bq * T * Dm;        // tiled [18][96][128][8]
    _Float16* woh = wqh + (size_t)3 * Dm * Dm;       // tiled [6][96][128][8]
    float* out = (float*)d_out;

    const int M = Bq * T;  // 8192

    // tiling converts: grid = R*96/256
    cvt_tile<<<dim3(M * 96 / 256), dim3(256), 0, stream>>>(x, xh);
    cvt_tile<<<dim3(3 * Dm * 96 / 256), dim3(256), 0, stream>>>(w_qkv, wqh);
    cvt_tile<<<dim3(Dm * 96 / 256), dim3(256), 0, stream>>>(w_out, woh);

    // qkv projection: grid 1152 = 18*64, %8==0 -> bijective XCD swizzle
    gemm_mfma<true><<<dim3((3 * Dm / 128) * (M / 128)), dim3(256), 0, stream>>>(
        xh, wqh, qb, kpd, vtb, nullptr, 3 * Dm, 3 * Dm / 128);

    attn_mfma<<<dim3(BH * (T / 64)), dim3(256), 0, stream>>>(qb, kpd, vtb, aoh);

    // out projection: grid 384 = 6*64, %8==0
    gemm_mfma<false><<<dim3((Dm / 128) * (M / 128)), dim3(256), 0, stream>>>(
        aoh, woh, nullptr, nullptr, nullptr, out, Dm, Dm / 128);
}